// Round 1
// baseline (2971.271 us; speedup 1.0000x reference)
//
#include <hip/hip_runtime.h>
#include <math.h>

#define CIN 32
#define COUT 64
#define DIM 48
#define PD 24

// Transpose weights [cout][cin][3][3][3] -> [cin][tap][cout] so a wave's
// 16 contiguous couts are one s_load_dwordx16.
__global__ __launch_bounds__(256) void wtrans_kernel(const float* __restrict__ w,
                                                     float* __restrict__ wT) {
    int i = blockIdx.x * 256 + threadIdx.x;            // 0 .. 55295
    if (i >= COUT * CIN * 27) return;
    int cout = i & 63;
    int tap  = (i >> 6) % 27;
    int cin  = i / (64 * 27);
    wT[i] = w[(cout * CIN + cin) * 27 + tap];
}

// One block: conv tile 4x4x4 (one conv position per lane), 4 waves x 16 couts.
// Fused: conv3d + bias + maxpool2 + logsumexp(ch) + relu.
template <bool TR>
__global__ __launch_bounds__(256) void conv_fused_kernel(
    const float* __restrict__ x, const float* __restrict__ wsrc,
    const float* __restrict__ bias, float* __restrict__ out)
{
    __shared__ float smem[CIN * 216];   // 27648 B; reused by epilogue

    const int tid = threadIdx.x;
    const int bid = blockIdx.x;
    const int tw = bid % 12, th = (bid / 12) % 12, td = (bid / 144) % 12, n = bid / 1728;
    const int d0 = td * 4, h0 = th * 4, w0 = tw * 4;

    // ---- stage x region [cin][6][6][6] with zero padding ----
    const float* xn = x + (size_t)n * CIN * DIM * DIM * DIM;
    for (int i = tid; i < CIN * 216; i += 256) {
        int cin = i / 216, r = i % 216;
        int dz = r / 36, hz = (r / 6) % 6, wz = r % 6;
        int gd = d0 - 1 + dz, gh = h0 - 1 + hz, gw = w0 - 1 + wz;
        float v = 0.f;
        if ((unsigned)gd < 48u && (unsigned)gh < 48u && (unsigned)gw < 48u)
            v = xn[((cin * DIM + gd) * DIM + gh) * DIM + gw];
        smem[i] = v;
    }
    __syncthreads();

    const int lane = tid & 63;
    const int wv = __builtin_amdgcn_readfirstlane(tid >> 6);  // wave-uniform
    const int cout0 = wv * 16;
    const int ld = lane >> 4, lh = (lane >> 2) & 3, lw = lane & 3;

    float acc[16];
#pragma unroll
    for (int c = 0; c < 16; ++c) acc[c] = 0.f;

    for (int cin = 0; cin < CIN; ++cin) {
        const int xb = cin * 216 + ld * 36 + lh * 6 + lw;
#pragma unroll
        for (int kd = 0; kd < 3; ++kd)
#pragma unroll
            for (int kh = 0; kh < 3; ++kh)
#pragma unroll
                for (int kw = 0; kw < 3; ++kw) {
                    const float xv = smem[xb + kd * 36 + kh * 6 + kw];
                    const int tap = (kd * 3 + kh) * 3 + kw;
#pragma unroll
                    for (int c = 0; c < 16; ++c) {
                        float wval;
                        if (TR)
                            wval = wsrc[(cin * 27 + tap) * 64 + cout0 + c];      // uniform -> s_load
                        else
                            wval = wsrc[((cout0 + c) * CIN + cin) * 27 + tap];   // fallback
                        acc[c] = fmaf(xv, wval, acc[c]);
                    }
                }
    }
    __syncthreads();   // done with x tile; reuse smem

    // ---- dump conv results: cb[wave][lane][16] ----
    float* cb = smem;  // 4*64*16 = 4096 floats
#pragma unroll
    for (int c = 0; c < 16; ++c) cb[(wv * 64 + lane) * 16 + c] = acc[c];
    __syncthreads();

    // ---- 2x2x2 max-pool + bias : pool[pp][cout], pp in 0..7 ----
    float* pool = smem + 4096;  // 512 floats
    for (int v = tid; v < 512; v += 256) {
        const int pp = v >> 6, c = v & 63;
        const int pd = pp >> 2, ph = (pp >> 1) & 1, pw = pp & 1;
        float m = -INFINITY;
#pragma unroll
        for (int i = 0; i < 2; ++i)
#pragma unroll
            for (int j = 0; j < 2; ++j)
#pragma unroll
                for (int k = 0; k < 2; ++k) {
                    const int l = ((2 * pd + i) << 4) | ((2 * ph + j) << 2) | (2 * pw + k);
                    m = fmaxf(m, cb[((c >> 4) * 64 + l) * 16 + (c & 15)]);
                }
        pool[pp * 64 + c] = m + bias[c];
    }
    __syncthreads();

    // ---- logsumexp over 64 channels + relu, 8 outputs per block ----
    if (tid < 8) {
        const int pd = tid >> 2, ph = (tid >> 1) & 1, pw = tid & 1;
        float m = -INFINITY;
        for (int c = 0; c < 64; ++c) m = fmaxf(m, pool[tid * 64 + c]);
        float s = 0.f;
        for (int c = 0; c < 64; ++c) s += __expf(pool[tid * 64 + c] - m);
        float r = fmaxf(m + logf(s), 0.f);
        const int dp = td * 2 + pd, hp = th * 2 + ph, wp = tw * 2 + pw;
        out[(((size_t)n * PD + dp) * PD + hp) * PD + wp] = r;
    }
}

extern "C" void kernel_launch(void* const* d_in, const int* in_sizes, int n_in,
                              void* d_out, int out_size, void* d_ws, size_t ws_size,
                              hipStream_t stream) {
    const float* x = (const float*)d_in[0];
    const float* w = (const float*)d_in[1];
    const float* b = (const float*)d_in[2];
    float* out = (float*)d_out;

    const int nblocks = 16 * 12 * 12 * 12;  // 27648
    if (ws_size >= (size_t)COUT * CIN * 27 * sizeof(float)) {
        float* wT = (float*)d_ws;
        wtrans_kernel<<<216, 256, 0, stream>>>(w, wT);
        conv_fused_kernel<true><<<nblocks, 256, 0, stream>>>(x, wT, b, out);
    } else {
        conv_fused_kernel<false><<<nblocks, 256, 0, stream>>>(x, w, b, out);
    }
}

// Round 2
// 644.689 us; speedup vs baseline: 4.6088x; 4.6088x over previous
//
#include <hip/hip_runtime.h>
#include <math.h>

#define CIN 32
#define COUT 64
#define DIM 48
#define PD 24

typedef __bf16 bf16x8 __attribute__((ext_vector_type(8)));
typedef float f32x4 __attribute__((ext_vector_type(4)));

__device__ __forceinline__ unsigned bf16_rne(float f) {
    unsigned u = __builtin_bit_cast(unsigned, f);
    return (u + 0x7fffu + ((u >> 16) & 1u)) >> 16;
}

// Pack weights [cout][cin][3][3][3] fp32 -> wg[tap][cout][cin] bf16
__global__ __launch_bounds__(256) void wpack_kernel(const float* __restrict__ w,
                                                    unsigned short* __restrict__ wg) {
    int i = blockIdx.x * 256 + threadIdx.x;  // 0 .. 55295
    if (i >= 27 * 64 * 32) return;
    int cin = i & 31, cout = (i >> 5) & 63, tap = i >> 11;
    float v = w[(cout * CIN + cin) * 27 + tap];
    wg[i] = (unsigned short)bf16_rne(v);
}

// Implicit-GEMM conv3d (bf16 MFMA) + bias + maxpool2 + logsumexp + relu.
// Block: 256 thr (4 waves), position tile (d,h,w)=(4,4,16), all 64 couts.
// Wave wv owns dz=wv; 4 hz M-tiles x 4 cout N-tiles accumulators.
__global__ __launch_bounds__(256, 3) void conv_mfma_kernel(
    const float* __restrict__ x, const unsigned short* __restrict__ wg,
    const float* __restrict__ bias, float* __restrict__ out)
{
    // x tile [ld 6][lh 6][lw 18][cin pad 40] bf16 = 51840 B
    __shared__ __align__(16) unsigned short xs[648 * 40];

    const int tid = threadIdx.x;
    const int bw = blockIdx.x % 3;
    const int bh = (blockIdx.x / 3) % 12;
    const int bd = (blockIdx.x / 36) % 12;
    const int n  = blockIdx.x / 432;
    const int d0 = bd * 4 - 1, h0 = bh * 4 - 1, w0 = bw * 16 - 1;

    // ---- stage x (fp32 -> bf16, cin pairs packed as u32) ----
    const float* xn = x + (size_t)n * CIN * DIM * DIM * DIM;
    for (int i = tid; i < 16 * 648; i += 256) {
        int cp = i / 648;            // cin pair 0..15
        int s  = i - cp * 648;       // spatial 0..647
        int lw = s % 18, t = s / 18, lh = t % 6, ld = t / 6;
        int gd = d0 + ld, gh = h0 + lh, gw = w0 + lw;
        unsigned pack = 0;
        if ((unsigned)gd < 48u && (unsigned)gh < 48u && (unsigned)gw < 48u) {
            const float* p = xn + ((size_t)(cp * 2) * DIM + gd) * DIM * DIM + gh * DIM + gw;
            pack = bf16_rne(p[0]) | (bf16_rne(p[DIM * DIM * DIM]) << 16);
        }
        ((unsigned*)xs)[s * 20 + cp] = pack;
    }
    __syncthreads();

    const int lane = tid & 63;
    const int wv = tid >> 6;        // dz
    const int m  = lane & 15;       // wz within M-tile / cout low bits
    const int ch = lane >> 4;       // k-chunk (A,B) / wz-group (C)

    f32x4 acc[4][4];                // [hz][cout-tile]
#pragma unroll
    for (int i = 0; i < 4; ++i)
#pragma unroll
        for (int j = 0; j < 4; ++j)
            acc[i][j] = (f32x4)0.f;

    const unsigned short* wgp = wg + m * 32 + ch * 8;

#pragma unroll
    for (int kd = 0; kd < 3; ++kd)
#pragma unroll
        for (int kh = 0; kh < 3; ++kh)
#pragma unroll
            for (int kw = 0; kw < 3; ++kw) {
                const int tap = (kd * 3 + kh) * 3 + kw;
                bf16x8 bfrag[4];
#pragma unroll
                for (int nt = 0; nt < 4; ++nt)
                    bfrag[nt] = *(const bf16x8*)(wgp + tap * 2048 + nt * 512);
#pragma unroll
                for (int hz = 0; hz < 4; ++hz) {
                    const int row = ((wv + kd) * 6 + (hz + kh)) * 18 + (m + kw);
                    bf16x8 afrag = *(const bf16x8*)(xs + row * 40 + ch * 8);
#pragma unroll
                    for (int nt = 0; nt < 4; ++nt)
                        acc[hz][nt] = __builtin_amdgcn_mfma_f32_16x16x32_bf16(
                            afrag, bfrag[nt], acc[hz][nt], 0, 0, 0);
                }
            }
    __syncthreads();  // done reading xs; reuse LDS

    // C/D layout: row(wz) = ch*4 + reg, col(cout) = nt*16 + m
    // ---- partial max over (hz pair, wz pair): pmax[dz 4][ph 2][pw 8][cout 64]
    float* pmax = (float*)xs;
#pragma unroll
    for (int ph = 0; ph < 2; ++ph)
#pragma unroll
        for (int b = 0; b < 2; ++b)
#pragma unroll
            for (int nt = 0; nt < 4; ++nt) {
                float v = fmaxf(
                    fmaxf(acc[2 * ph][nt][2 * b], acc[2 * ph][nt][2 * b + 1]),
                    fmaxf(acc[2 * ph + 1][nt][2 * b], acc[2 * ph + 1][nt][2 * b + 1]));
                int pw = 2 * ch + b;
                pmax[((wv * 2 + ph) * 8 + pw) * 64 + nt * 16 + m] = v;
            }
    __syncthreads();

    // ---- dz-pair max + bias -> pooled[cell 32][cout pad 65]
    float* pooled = pmax + 4096;
    for (int v = tid; v < 2048; v += 256) {
        int c = v & 63, cell = v >> 6;                 // cell = (pd*2+ph)*8+pw
        int pd = cell >> 4, ph = (cell >> 3) & 1, pw = cell & 7;
        int i1 = ((4 * pd + ph) * 8 + pw) * 64 + c;
        pooled[cell * 65 + c] = fmaxf(pmax[i1], pmax[i1 + 1024]) + bias[c];
    }
    __syncthreads();

    // ---- logsumexp over 64 ch + relu, 32 outputs/block
    if (tid < 32) {
        int pd = tid >> 4, ph = (tid >> 3) & 1, pw = tid & 7;
        float mx = -INFINITY;
        for (int c = 0; c < 64; ++c) mx = fmaxf(mx, pooled[tid * 65 + c]);
        float s = 0.f;
        for (int c = 0; c < 64; ++c) s += __expf(pooled[tid * 65 + c] - mx);
        float r = fmaxf(mx + __logf(s), 0.f);
        int od = bd * 2 + pd, oh = bh * 2 + ph, ow = bw * 8 + pw;
        out[((size_t)(n * PD + od) * PD + oh) * PD + ow] = r;
    }
}

// ---------------- fallback (fp32, no workspace) — round-1 kernel ----------------
__global__ __launch_bounds__(256) void conv_fused_fallback(
    const float* __restrict__ x, const float* __restrict__ wsrc,
    const float* __restrict__ bias, float* __restrict__ out)
{
    __shared__ float smem[CIN * 216];
    const int tid = threadIdx.x;
    const int bid = blockIdx.x;
    const int tw = bid % 12, th = (bid / 12) % 12, td = (bid / 144) % 12, n = bid / 1728;
    const int d0 = td * 4, h0 = th * 4, w0 = tw * 4;
    const float* xn = x + (size_t)n * CIN * DIM * DIM * DIM;
    for (int i = tid; i < CIN * 216; i += 256) {
        int cin = i / 216, r = i % 216;
        int dz = r / 36, hz = (r / 6) % 6, wz = r % 6;
        int gd = d0 - 1 + dz, gh = h0 - 1 + hz, gw = w0 - 1 + wz;
        float v = 0.f;
        if ((unsigned)gd < 48u && (unsigned)gh < 48u && (unsigned)gw < 48u)
            v = xn[((cin * DIM + gd) * DIM + gh) * DIM + gw];
        smem[i] = v;
    }
    __syncthreads();
    const int lane = tid & 63;
    const int wv = __builtin_amdgcn_readfirstlane(tid >> 6);
    const int cout0 = wv * 16;
    const int ld = lane >> 4, lh = (lane >> 2) & 3, lw = lane & 3;
    float acc[16];
#pragma unroll
    for (int c = 0; c < 16; ++c) acc[c] = 0.f;
    for (int cin = 0; cin < CIN; ++cin) {
        const int xb = cin * 216 + ld * 36 + lh * 6 + lw;
#pragma unroll
        for (int kd = 0; kd < 3; ++kd)
#pragma unroll
            for (int kh = 0; kh < 3; ++kh)
#pragma unroll
                for (int kw = 0; kw < 3; ++kw) {
                    const float xv = smem[xb + kd * 36 + kh * 6 + kw];
                    const int tap = (kd * 3 + kh) * 3 + kw;
#pragma unroll
                    for (int c = 0; c < 16; ++c)
                        acc[c] = fmaf(xv, wsrc[((cout0 + c) * CIN + cin) * 27 + tap], acc[c]);
                }
    }
    __syncthreads();
    float* cb = smem;
#pragma unroll
    for (int c = 0; c < 16; ++c) cb[(wv * 64 + lane) * 16 + c] = acc[c];
    __syncthreads();
    float* pool = smem + 4096;
    for (int v = tid; v < 512; v += 256) {
        const int pp = v >> 6, c = v & 63;
        const int pd = pp >> 2, ph = (pp >> 1) & 1, pw = pp & 1;
        float mv = -INFINITY;
#pragma unroll
        for (int i = 0; i < 2; ++i)
#pragma unroll
            for (int j = 0; j < 2; ++j)
#pragma unroll
                for (int k = 0; k < 2; ++k) {
                    const int l = ((2 * pd + i) << 4) | ((2 * ph + j) << 2) | (2 * pw + k);
                    mv = fmaxf(mv, cb[((c >> 4) * 64 + l) * 16 + (c & 15)]);
                }
        pool[pp * 64 + c] = mv + bias[c];
    }
    __syncthreads();
    if (tid < 8) {
        float mx = -INFINITY;
        for (int c = 0; c < 64; ++c) mx = fmaxf(mx, pool[tid * 64 + c]);
        float s = 0.f;
        for (int c = 0; c < 64; ++c) s += __expf(pool[tid * 64 + c] - mx);
        float r = fmaxf(mx + logf(s), 0.f);
        const int pd = tid >> 2, ph = (tid >> 1) & 1, pw = tid & 1;
        const int dp = td * 2 + pd, hp = th * 2 + ph, wp = tw * 2 + pw;
        out[(((size_t)n * PD + dp) * PD + hp) * PD + wp] = r;
    }
}

extern "C" void kernel_launch(void* const* d_in, const int* in_sizes, int n_in,
                              void* d_out, int out_size, void* d_ws, size_t ws_size,
                              hipStream_t stream) {
    const float* x = (const float*)d_in[0];
    const float* w = (const float*)d_in[1];
    const float* b = (const float*)d_in[2];
    float* out = (float*)d_out;

    if (ws_size >= (size_t)(27 * 64 * 32) * sizeof(unsigned short)) {
        unsigned short* wgb = (unsigned short*)d_ws;
        wpack_kernel<<<216, 256, 0, stream>>>(w, wgb);
        conv_mfma_kernel<<<16 * 12 * 12 * 3, 256, 0, stream>>>(x, wgb, b, out);
    } else {
        conv_fused_fallback<<<16 * 12 * 12 * 12, 256, 0, stream>>>(x, w, b, out);
    }
}

// Round 3
// 552.579 us; speedup vs baseline: 5.3771x; 1.1667x over previous
//
#include <hip/hip_runtime.h>
#include <math.h>

#define CIN 32
#define COUT 64
#define DIM 48
#define PD 24
#define D3 110592  // 48^3

typedef __bf16 bf16x8 __attribute__((ext_vector_type(8)));
typedef float f32x4 __attribute__((ext_vector_type(4)));

__device__ __forceinline__ unsigned bf16_rne(float f) {
    unsigned u = __builtin_bit_cast(unsigned, f);
    return (u + 0x7fffu + ((u >> 16) & 1u)) >> 16;
}

// Pack weights [cout][cin][3][3][3] fp32 -> wg[tap][cout][cin] bf16
__global__ __launch_bounds__(256) void wpack_kernel(const float* __restrict__ w,
                                                    unsigned short* __restrict__ wg) {
    int i = blockIdx.x * 256 + threadIdx.x;  // 0 .. 55295
    if (i >= 27 * 64 * 32) return;
    int cin = i & 31, cout = (i >> 5) & 63, tap = i >> 11;
    float v = w[(cout * CIN + cin) * 27 + tap];
    wg[i] = (unsigned short)bf16_rne(v);
}

// Implicit-GEMM conv3d (bf16 MFMA) + bias + maxpool2 + logsumexp + relu.
// Block: 256 thr (4 waves), position tile (d,h,w)=(4,4,16), all 64 couts.
// Wave wv owns dz=wv; 4 hz M-tiles x 4 cout N-tiles accumulators.
// R3: software-pipelined B prefetch (regs) + batched staging loads.
__global__ __launch_bounds__(256, 3) void conv_mfma_kernel(
    const float* __restrict__ x, const unsigned short* __restrict__ wg,
    const float* __restrict__ bias, float* __restrict__ out)
{
    // x tile [ld 6][lh 6][lw 18][cin pad 40] bf16 = 51840 B
    __shared__ __align__(16) unsigned short xs[648 * 40];

    const int tid = threadIdx.x;
    const int bw = blockIdx.x % 3;
    const int bh = (blockIdx.x / 3) % 12;
    const int bd = (blockIdx.x / 36) % 12;
    const int n  = blockIdx.x / 432;
    const int d0 = bd * 4 - 1, h0 = bh * 4 - 1, w0 = bw * 16 - 1;

    // ---- stage x (fp32 -> bf16, cin pairs packed as u32), batched loads ----
    const float* xn = x + (size_t)n * CIN * D3;
    {
        const int cp = tid >> 4;   // cin pair 0..15
        const int sl = tid & 15;   // spatial lane 0..15
        const float* xp0 = xn + (size_t)(cp * 2) * D3;
        for (int itb = 0; itb < 6; ++itb) {
            float f0[8], f1[8];
            int sv[8];
#pragma unroll
            for (int u = 0; u < 8; ++u) {
                const int s = sl + ((itb * 8 + u) << 4);
                sv[u] = s;
                f0[u] = 0.f; f1[u] = 0.f;
                if (s < 648) {
                    const int lw = s % 18, t = s / 18, lh = t % 6, ld = t / 6;
                    const int gd = d0 + ld, gh = h0 + lh, gw = w0 + lw;
                    if ((unsigned)gd < 48u && (unsigned)gh < 48u && (unsigned)gw < 48u) {
                        const float* p = xp0 + (gd * DIM + gh) * DIM + gw;
                        f0[u] = p[0];
                        f1[u] = p[D3];
                    }
                }
            }
#pragma unroll
            for (int u = 0; u < 8; ++u)
                if (sv[u] < 648)
                    ((unsigned*)xs)[sv[u] * 20 + cp] =
                        bf16_rne(f0[u]) | (bf16_rne(f1[u]) << 16);
        }
    }

    const int lane = tid & 63;
    const int wv = tid >> 6;        // dz
    const int m  = lane & 15;       // wz within M-tile / cout low bits
    const int ch = lane >> 4;       // k-chunk (A,B) / wz-group (C)

    const unsigned short* wgp = wg + m * 32 + ch * 8;

    // prefetch tap 0's B-fragments BEFORE the barrier (in flight during sync)
    bf16x8 bcur[4], bnxt[4];
#pragma unroll
    for (int nt = 0; nt < 4; ++nt)
        bcur[nt] = *(const bf16x8*)(wgp + nt * 512);

    __syncthreads();

    f32x4 acc[4][4];                // [hz][cout-tile]
#pragma unroll
    for (int i = 0; i < 4; ++i)
#pragma unroll
        for (int j = 0; j < 4; ++j)
            acc[i][j] = (f32x4)0.f;

#pragma unroll
    for (int tap = 0; tap < 27; ++tap) {
        if (tap < 26) {
#pragma unroll
            for (int nt = 0; nt < 4; ++nt)
                bnxt[nt] = *(const bf16x8*)(wgp + (tap + 1) * 2048 + nt * 512);
        }
        const int kd = tap / 9, kh = (tap / 3) % 3, kw = tap % 3;
        bf16x8 af[4];
#pragma unroll
        for (int hz = 0; hz < 4; ++hz) {
            const int row = ((wv + kd) * 6 + (hz + kh)) * 18 + (m + kw);
            af[hz] = *(const bf16x8*)(xs + row * 40 + ch * 8);
        }
#pragma unroll
        for (int hz = 0; hz < 4; ++hz)
#pragma unroll
            for (int nt = 0; nt < 4; ++nt)
                acc[hz][nt] = __builtin_amdgcn_mfma_f32_16x16x32_bf16(
                    af[hz], bcur[nt], acc[hz][nt], 0, 0, 0);
#pragma unroll
        for (int nt = 0; nt < 4; ++nt) bcur[nt] = bnxt[nt];
    }
    __syncthreads();  // done reading xs; reuse LDS

    // C/D layout: row(wz) = ch*4 + reg, col(cout) = nt*16 + m
    // ---- partial max over (hz pair, wz pair): pmax[dz 4][ph 2][pw 8][cout 64]
    float* pmax = (float*)xs;
#pragma unroll
    for (int ph = 0; ph < 2; ++ph)
#pragma unroll
        for (int b = 0; b < 2; ++b)
#pragma unroll
            for (int nt = 0; nt < 4; ++nt) {
                float v = fmaxf(
                    fmaxf(acc[2 * ph][nt][2 * b], acc[2 * ph][nt][2 * b + 1]),
                    fmaxf(acc[2 * ph + 1][nt][2 * b], acc[2 * ph + 1][nt][2 * b + 1]));
                int pw = 2 * ch + b;
                pmax[((wv * 2 + ph) * 8 + pw) * 64 + nt * 16 + m] = v;
            }
    __syncthreads();

    // ---- dz-pair max + bias -> pooled[cell 32][cout pad 65]
    float* pooled = pmax + 4096;
    for (int v = tid; v < 2048; v += 256) {
        int c = v & 63, cell = v >> 6;                 // cell = (pd*2+ph)*8+pw
        int pd = cell >> 4, ph = (cell >> 3) & 1, pw = cell & 7;
        int i1 = ((4 * pd + ph) * 8 + pw) * 64 + c;
        pooled[cell * 65 + c] = fmaxf(pmax[i1], pmax[i1 + 1024]) + bias[c];
    }
    __syncthreads();

    // ---- logsumexp over 64 ch + relu, 32 outputs/block
    if (tid < 32) {
        int pd = tid >> 4, ph = (tid >> 3) & 1, pw = tid & 7;
        float mx = -INFINITY;
        for (int c = 0; c < 64; ++c) mx = fmaxf(mx, pooled[tid * 65 + c]);
        float s = 0.f;
        for (int c = 0; c < 64; ++c) s += __expf(pooled[tid * 65 + c] - mx);
        float r = fmaxf(mx + __logf(s), 0.f);
        int od = bd * 2 + pd, oh = bh * 2 + ph, ow = bw * 8 + pw;
        out[((size_t)(n * PD + od) * PD + oh) * PD + ow] = r;
    }
}

// ---------------- fallback (fp32, no workspace) ----------------
__global__ __launch_bounds__(256) void conv_fused_fallback(
    const float* __restrict__ x, const float* __restrict__ wsrc,
    const float* __restrict__ bias, float* __restrict__ out)
{
    __shared__ float smem[CIN * 216];
    const int tid = threadIdx.x;
    const int bid = blockIdx.x;
    const int tw = bid % 12, th = (bid / 12) % 12, td = (bid / 144) % 12, n = bid / 1728;
    const int d0 = td * 4, h0 = th * 4, w0 = tw * 4;
    const float* xn = x + (size_t)n * CIN * D3;
    for (int i = tid; i < CIN * 216; i += 256) {
        int cin = i / 216, r = i % 216;
        int dz = r / 36, hz = (r / 6) % 6, wz = r % 6;
        int gd = d0 - 1 + dz, gh = h0 - 1 + hz, gw = w0 - 1 + wz;
        float v = 0.f;
        if ((unsigned)gd < 48u && (unsigned)gh < 48u && (unsigned)gw < 48u)
            v = xn[((cin * DIM + gd) * DIM + gh) * DIM + gw];
        smem[i] = v;
    }
    __syncthreads();
    const int lane = tid & 63;
    const int wv = __builtin_amdgcn_readfirstlane(tid >> 6);
    const int cout0 = wv * 16;
    const int ld = lane >> 4, lh = (lane >> 2) & 3, lw = lane & 3;
    float acc[16];
#pragma unroll
    for (int c = 0; c < 16; ++c) acc[c] = 0.f;
    for (int cin = 0; cin < CIN; ++cin) {
        const int xb = cin * 216 + ld * 36 + lh * 6 + lw;
#pragma unroll
        for (int kd = 0; kd < 3; ++kd)
#pragma unroll
            for (int kh = 0; kh < 3; ++kh)
#pragma unroll
                for (int kw = 0; kw < 3; ++kw) {
                    const float xv = smem[xb + kd * 36 + kh * 6 + kw];
                    const int tap = (kd * 3 + kh) * 3 + kw;
#pragma unroll
                    for (int c = 0; c < 16; ++c)
                        acc[c] = fmaf(xv, wsrc[((cout0 + c) * CIN + cin) * 27 + tap], acc[c]);
                }
    }
    __syncthreads();
    float* cb = smem;
#pragma unroll
    for (int c = 0; c < 16; ++c) cb[(wv * 64 + lane) * 16 + c] = acc[c];
    __syncthreads();
    float* pool = smem + 4096;
    for (int v = tid; v < 512; v += 256) {
        const int pp = v >> 6, c = v & 63;
        const int pd = pp >> 2, ph = (pp >> 1) & 1, pw = pp & 1;
        float mv = -INFINITY;
#pragma unroll
        for (int i = 0; i < 2; ++i)
#pragma unroll
            for (int j = 0; j < 2; ++j)
#pragma unroll
                for (int k = 0; k < 2; ++k) {
                    const int l = ((2 * pd + i) << 4) | ((2 * ph + j) << 2) | (2 * pw + k);
                    mv = fmaxf(mv, cb[((c >> 4) * 64 + l) * 16 + (c & 15)]);
                }
        pool[pp * 64 + c] = mv + bias[c];
    }
    __syncthreads();
    if (tid < 8) {
        float mx = -INFINITY;
        for (int c = 0; c < 64; ++c) mx = fmaxf(mx, pool[tid * 64 + c]);
        float s = 0.f;
        for (int c = 0; c < 64; ++c) s += __expf(pool[tid * 64 + c] - mx);
        float r = fmaxf(mx + logf(s), 0.f);
        const int pd = tid >> 2, ph = (tid >> 1) & 1, pw = tid & 1;
        const int dp = td * 2 + pd, hp = th * 2 + ph, wp = tw * 2 + pw;
        out[(((size_t)n * PD + dp) * PD + hp) * PD + wp] = r;
    }
}

extern "C" void kernel_launch(void* const* d_in, const int* in_sizes, int n_in,
                              void* d_out, int out_size, void* d_ws, size_t ws_size,
                              hipStream_t stream) {
    const float* x = (const float*)d_in[0];
    const float* w = (const float*)d_in[1];
    const float* b = (const float*)d_in[2];
    float* out = (float*)d_out;

    if (ws_size >= (size_t)(27 * 64 * 32) * sizeof(unsigned short)) {
        unsigned short* wgb = (unsigned short*)d_ws;
        wpack_kernel<<<216, 256, 0, stream>>>(w, wgb);
        conv_mfma_kernel<<<16 * 12 * 12 * 3, 256, 0, stream>>>(x, wgb, b, out);
    } else {
        conv_fused_fallback<<<16 * 12 * 12 * 12, 256, 0, stream>>>(x, w, b, out);
    }
}